// Round 4
// baseline (142.871 us; speedup 1.0000x reference)
//
#include <hip/hip_runtime.h>

// QuantizedLinear: y[b][o] = scale * sum_k x[b][k]*(qw[o][k]-zp) + bias[o]
// M=16, K=8192, N=8192, all f32. Memory-bound on qw (256 MB read once).
// Floor ~41 us @ 6.3 TB/s.
//
// R3 (resubmit after infra failure): R1's proven structure (full-wave 1KB qw
// loads, 4 rows/wave, butterfly reduce) + K-split x2 through d_ws (coalesced
// partial stores, NO atomics) + 1-iteration qw register prefetch. 4096 waves
// -> 4/SIMD; prefetch cuts exposed HBM latency. launch_bounds(256,4) pins
// VGPR <= 128.

constexpr int IN_F  = 8192;
constexpr int OUT_F = 8192;
constexpr int BATCH = 16;
constexpr int R     = 4;     // output rows per wave
constexpr int WPB   = 4;     // waves per block (256 threads)
constexpr int KBLK  = 256;   // k per wave-iteration (64 lanes x float4)
constexpr int ROWBLOCKS = OUT_F / (WPB * R);   // 512

template <int NSEG>
__global__ __launch_bounds__(WPB * 64, 4)
void qlinear_stage1(const float* __restrict__ x,    // [BATCH][IN_F]
                    const float* __restrict__ qw,   // [OUT_F][IN_F]
                    const float* __restrict__ zp_p,
                    float* __restrict__ part)       // [NSEG][BATCH][OUT_F]
{
    constexpr int SEG   = IN_F / NSEG;
    constexpr int ITERS = SEG / KBLK;

    const int lane = threadIdx.x & 63;
    const int wave = threadIdx.x >> 6;
    const int seg     = blockIdx.x / ROWBLOCKS;
    const int rowBlk  = blockIdx.x - seg * ROWBLOCKS;
    const int rowBase = (rowBlk * WPB + wave) * R;
    const int kseg    = seg * SEG;

    const float zp = zp_p[0];

    float acc[BATCH][R];
#pragma unroll
    for (int b = 0; b < BATCH; ++b)
#pragma unroll
        for (int r = 0; r < R; ++r) acc[b][r] = 0.0f;

    // Prologue: load iter-0 qw fragments.
    float4 wq[R];
#pragma unroll
    for (int r = 0; r < R; ++r)
        wq[r] = *reinterpret_cast<const float4*>(
            qw + (size_t)(rowBase + r) * IN_F + kseg + lane * 4);

    auto compute = [&](int it, const float4 (&w4)[R]) {
        const int k = kseg + it * KBLK + lane * 4;
        float w[R][4];
#pragma unroll
        for (int r = 0; r < R; ++r) {
            w[r][0] = w4[r].x - zp;
            w[r][1] = w4[r].y - zp;
            w[r][2] = w4[r].z - zp;
            w[r][3] = w4[r].w - zp;
        }
#pragma unroll
        for (int g = 0; g < 4; ++g) {
            float4 xv[4];
#pragma unroll
            for (int j = 0; j < 4; ++j)
                xv[j] = *reinterpret_cast<const float4*>(
                    x + (g * 4 + j) * IN_F + k);
#pragma unroll
            for (int j = 0; j < 4; ++j) {
                const int b = g * 4 + j;
#pragma unroll
                for (int r = 0; r < R; ++r) {
                    acc[b][r] += xv[j].x * w[r][0];
                    acc[b][r] += xv[j].y * w[r][1];
                    acc[b][r] += xv[j].z * w[r][2];
                    acc[b][r] += xv[j].w * w[r][3];
                }
            }
        }
    };

    for (int it = 0; it < ITERS - 1; ++it) {
        // Prefetch next iteration's qw while computing current.
        float4 wn[R];
        const int kn = kseg + (it + 1) * KBLK + lane * 4;
#pragma unroll
        for (int r = 0; r < R; ++r)
            wn[r] = *reinterpret_cast<const float4*>(
                qw + (size_t)(rowBase + r) * IN_F + kn);
        compute(it, wq);
#pragma unroll
        for (int r = 0; r < R; ++r) wq[r] = wn[r];
    }
    compute(ITERS - 1, wq);

    // Butterfly-reduce each accumulator across the 64 lanes.
#pragma unroll
    for (int b = 0; b < BATCH; ++b)
#pragma unroll
        for (int r = 0; r < R; ++r) {
#pragma unroll
            for (int s = 32; s >= 1; s >>= 1)
                acc[b][r] += __shfl_xor(acc[b][r], s, 64);
        }

    // Lane (b*4+r) emits acc[b][r] (raw sum; scale+bias applied in stage 2).
    float val = 0.0f;
#pragma unroll
    for (int b = 0; b < BATCH; ++b)
#pragma unroll
        for (int r = 0; r < R; ++r)
            if (lane == b * R + r) val = acc[b][r];

    const int b = lane >> 2;
    const int r = lane & 3;
    part[((size_t)seg * BATCH + b) * OUT_F + rowBase + r] = val;
}

// y = scale * (part[0] + part[1]) + bias
__global__ __launch_bounds__(256)
void qlinear_stage2(const float* __restrict__ part,
                    const float* __restrict__ scale_p,
                    const float* __restrict__ bias,
                    float* __restrict__ y)
{
    const int i = (blockIdx.x * 256 + threadIdx.x) * 4;  // over BATCH*OUT_F
    const float s = scale_p[0];
    const float4 p0 = *reinterpret_cast<const float4*>(part + i);
    const float4 p1 = *reinterpret_cast<const float4*>(part + (size_t)BATCH * OUT_F + i);
    const float4 bv = *reinterpret_cast<const float4*>(bias + (i & (OUT_F - 1)));
    float4 out;
    out.x = s * (p0.x + p1.x) + bv.x;
    out.y = s * (p0.y + p1.y) + bv.y;
    out.z = s * (p0.z + p1.z) + bv.z;
    out.w = s * (p0.w + p1.w) + bv.w;
    *reinterpret_cast<float4*>(y + i) = out;
}

// Fallback (ws too small): y = scale * y + bias, in place after stage1<1>.
__global__ __launch_bounds__(256)
void qlinear_finish1(const float* __restrict__ scale_p,
                     const float* __restrict__ bias,
                     float* __restrict__ y)
{
    const int i = (blockIdx.x * 256 + threadIdx.x) * 4;
    const float s = scale_p[0];
    float4 p = *reinterpret_cast<float4*>(y + i);
    const float4 bv = *reinterpret_cast<const float4*>(bias + (i & (OUT_F - 1)));
    p.x = s * p.x + bv.x;
    p.y = s * p.y + bv.y;
    p.z = s * p.z + bv.z;
    p.w = s * p.w + bv.w;
    *reinterpret_cast<float4*>(y + i) = p;
}

extern "C" void kernel_launch(void* const* d_in, const int* in_sizes, int n_in,
                              void* d_out, int out_size, void* d_ws, size_t ws_size,
                              hipStream_t stream) {
    const float* x     = (const float*)d_in[0];
    const float* qw    = (const float*)d_in[1];
    const float* scale = (const float*)d_in[2];
    const float* zp    = (const float*)d_in[3];
    const float* bias  = (const float*)d_in[4];
    float* y = (float*)d_out;

    const size_t part_bytes = (size_t)2 * BATCH * OUT_F * sizeof(float);  // 1 MB
    const int n_elem_blocks = (BATCH * OUT_F / 4) / 256;                  // 128

    if (ws_size >= part_bytes) {
        float* part = (float*)d_ws;
        qlinear_stage1<2><<<2 * ROWBLOCKS, WPB * 64, 0, stream>>>(x, qw, zp, part);
        qlinear_stage2<<<n_elem_blocks, 256, 0, stream>>>(part, scale, bias, y);
    } else {
        qlinear_stage1<1><<<ROWBLOCKS, WPB * 64, 0, stream>>>(x, qw, zp, y);
        qlinear_finish1<<<n_elem_blocks, 256, 0, stream>>>(scale, bias, y);
    }
}

// Round 5
// 87.115 us; speedup vs baseline: 1.6400x; 1.6400x over previous
//
#include <hip/hip_runtime.h>

// QuantizedLinear: y[b][o] = scale * sum_k x[b][k]*(qw[o][k]-zp) + bias[o]
// M=16, K=8192, N=8192, all f32. Memory-bound on qw (256 MB read once).
// Floor ~41 us @ 6.3 TB/s.
//
// R5: R1's proven loop (full-wave 1KB qw loads, 4 rows/wave, butterfly
// reduce, NO manual prefetch, NO launch_bounds min-waves -- R4 showed the
// forced cap spills accumulators: VGPR=64 + 45MB scratch writes).
// Concurrency from KSPLIT=2 through d_ws (4096 waves = 4/SIMD).
// zp handled algebraically: sum(q-zp)*x = sum(q*x) - zp*sum(x), so the hot
// loop FMAs raw q (no per-element sub, no conversion registers).

constexpr int IN_F  = 8192;
constexpr int OUT_F = 8192;
constexpr int BATCH = 16;
constexpr int R     = 4;     // output rows per wave
constexpr int WPB   = 4;     // waves per block (256 threads)
constexpr int KBLK  = 256;   // k per wave-iteration (64 lanes x float4)
constexpr int NSEG  = 2;
constexpr int SEG   = IN_F / NSEG;             // 4096
constexpr int ITERS = SEG / KBLK;              // 16
constexpr int ROWBLOCKS = OUT_F / (WPB * R);   // 512

// sumx[b] = sum_k x[b][k]  (for the algebraic zero-point correction)
__global__ __launch_bounds__(64)
void sumx_kernel(const float* __restrict__ x, float* __restrict__ sumx) {
    const int b = blockIdx.x;
    const int lane = threadIdx.x;
    float s = 0.0f;
    for (int i = lane * 4; i < IN_F; i += 64 * 4) {
        const float4 v = *reinterpret_cast<const float4*>(x + b * IN_F + i);
        s += v.x + v.y + v.z + v.w;
    }
#pragma unroll
    for (int d = 32; d >= 1; d >>= 1) s += __shfl_xor(s, d, 64);
    if (lane == 0) sumx[b] = s;
}

__global__ __launch_bounds__(WPB * 64)
void qlinear_stage1(const float* __restrict__ x,    // [BATCH][IN_F]
                    const float* __restrict__ qw,   // [OUT_F][IN_F]
                    float* __restrict__ part)       // [NSEG][BATCH][OUT_F]
{
    const int lane = threadIdx.x & 63;
    const int wave = threadIdx.x >> 6;
    const int seg     = blockIdx.x / ROWBLOCKS;
    const int rowBlk  = blockIdx.x - seg * ROWBLOCKS;
    const int rowBase = (rowBlk * WPB + wave) * R;
    const int kseg    = seg * SEG;

    float acc[BATCH][R];
#pragma unroll
    for (int b = 0; b < BATCH; ++b)
#pragma unroll
        for (int r = 0; r < R; ++r) acc[b][r] = 0.0f;

    for (int it = 0; it < ITERS; ++it) {
        const int k = kseg + it * KBLK + lane * 4;

        float4 q[R];
#pragma unroll
        for (int r = 0; r < R; ++r)
            q[r] = *reinterpret_cast<const float4*>(
                qw + (size_t)(rowBase + r) * IN_F + k);

#pragma unroll
        for (int g = 0; g < 4; ++g) {
            float4 xv[4];
#pragma unroll
            for (int j = 0; j < 4; ++j)
                xv[j] = *reinterpret_cast<const float4*>(
                    x + (g * 4 + j) * IN_F + k);
#pragma unroll
            for (int j = 0; j < 4; ++j) {
                const int b = g * 4 + j;
#pragma unroll
                for (int r = 0; r < R; ++r) {
                    acc[b][r] += xv[j].x * q[r].x;
                    acc[b][r] += xv[j].y * q[r].y;
                    acc[b][r] += xv[j].z * q[r].z;
                    acc[b][r] += xv[j].w * q[r].w;
                }
            }
        }
    }

    // Butterfly-reduce each accumulator across the 64 lanes.
#pragma unroll
    for (int b = 0; b < BATCH; ++b)
#pragma unroll
        for (int r = 0; r < R; ++r) {
#pragma unroll
            for (int s = 32; s >= 1; s >>= 1)
                acc[b][r] += __shfl_xor(acc[b][r], s, 64);
        }

    // Lane (b*4+r) emits acc[b][r] (raw q-sum; zp/scale/bias in stage 2).
    float val = 0.0f;
#pragma unroll
    for (int b = 0; b < BATCH; ++b)
#pragma unroll
        for (int r = 0; r < R; ++r)
            if (lane == b * R + r) val = acc[b][r];

    const int b = lane >> 2;
    const int r = lane & 3;
    part[((size_t)seg * BATCH + b) * OUT_F + rowBase + r] = val;
}

// y = scale * (p0 + p1 - zp * sumx[b]) + bias
__global__ __launch_bounds__(256)
void qlinear_stage2(const float* __restrict__ part,
                    const float* __restrict__ sumx,
                    const float* __restrict__ scale_p,
                    const float* __restrict__ zp_p,
                    const float* __restrict__ bias,
                    float* __restrict__ y)
{
    const int i = (blockIdx.x * 256 + threadIdx.x) * 4;  // over BATCH*OUT_F
    const float s  = scale_p[0];
    const float zc = zp_p[0] * sumx[i >> 13];            // b = i / OUT_F
    const float4 p0 = *reinterpret_cast<const float4*>(part + i);
    const float4 p1 = *reinterpret_cast<const float4*>(part + (size_t)BATCH * OUT_F + i);
    const float4 bv = *reinterpret_cast<const float4*>(bias + (i & (OUT_F - 1)));
    float4 out;
    out.x = s * (p0.x + p1.x - zc) + bv.x;
    out.y = s * (p0.y + p1.y - zc) + bv.y;
    out.z = s * (p0.z + p1.z - zc) + bv.z;
    out.w = s * (p0.w + p1.w - zc) + bv.w;
    *reinterpret_cast<float4*>(y + i) = out;
}

extern "C" void kernel_launch(void* const* d_in, const int* in_sizes, int n_in,
                              void* d_out, int out_size, void* d_ws, size_t ws_size,
                              hipStream_t stream) {
    const float* x     = (const float*)d_in[0];
    const float* qw    = (const float*)d_in[1];
    const float* scale = (const float*)d_in[2];
    const float* zp    = (const float*)d_in[3];
    const float* bias  = (const float*)d_in[4];
    float* y = (float*)d_out;

    float* part = (float*)d_ws;                           // NSEG*BATCH*OUT_F floats (1 MB)
    float* sumx = part + (size_t)NSEG * BATCH * OUT_F;    // BATCH floats

    sumx_kernel<<<BATCH, 64, 0, stream>>>(x, sumx);
    qlinear_stage1<<<NSEG * ROWBLOCKS, WPB * 64, 0, stream>>>(x, qw, part);
    const int n_elem_blocks = (BATCH * OUT_F / 4) / 256;  // 128
    qlinear_stage2<<<n_elem_blocks, 256, 0, stream>>>(part, sumx, scale, zp, bias, y);
}

// Round 7
// 67.630 us; speedup vs baseline: 2.1125x; 1.2881x over previous
//
#include <hip/hip_runtime.h>
#include <hip/hip_bf16.h>

// QuantizedLinear: y[b][o] = scale * sum_k x[b][k]*(qw[o][k]-zp) + bias[o]
// M=16, K=8192, N=8192. qw integers 0..255 -> EXACT in bf16; harness compares
// in bf16 domain (threshold 21.92) -> bf16 MFMA is safe.
//
// R6 resubmit (infra failure, never measured): MFMA formulation. Per
// 16x16x32 tile: 2 qw loads + 1 x-frag load + 8 cvt + 1 MFMA (vs R5's
// 20 VMEM + ~300 VALU per 4KB). x pre-converted to bf16 once (256 KB in ws).
// KSPLIT=8 partials in ws, no atomics, no forced launch_bounds (R4: forced
// cap spilled accumulators).

constexpr int IN_F  = 8192;
constexpr int OUT_F = 8192;
constexpr int BATCH = 16;
constexpr int KSPLIT = 8;
constexpr int SEG    = IN_F / KSPLIT;   // 1024
constexpr int ITERS  = SEG / 32;        // 32 MFMAs per wave
constexpr int NT     = OUT_F / 16;      // 512 n-tiles
constexpr int WPB    = 4;               // waves per block

typedef __attribute__((ext_vector_type(8))) short bf16x8;
typedef __attribute__((ext_vector_type(4))) float f32x4;

__device__ inline short f2bf(float f) {
    __hip_bfloat16 h = __float2bfloat16(f);
    return __builtin_bit_cast(short, h);
}

// xbf[b][k] = bf16(x[b][k]); sumx[b] = sum_k x[b][k]  (zp correction)
__global__ __launch_bounds__(64)
void prep_kernel(const float* __restrict__ x, unsigned short* __restrict__ xbf,
                 float* __restrict__ sumx) {
    const int b = blockIdx.x;
    const int lane = threadIdx.x;
    float s = 0.0f;
    for (int i = lane * 4; i < IN_F; i += 64 * 4) {
        const float4 v = *reinterpret_cast<const float4*>(x + b * IN_F + i);
        s += v.x + v.y + v.z + v.w;
        ushort4 u;
        u.x = (unsigned short)f2bf(v.x);
        u.y = (unsigned short)f2bf(v.y);
        u.z = (unsigned short)f2bf(v.z);
        u.w = (unsigned short)f2bf(v.w);
        *reinterpret_cast<ushort4*>(xbf + b * IN_F + i) = u;
    }
#pragma unroll
    for (int d = 32; d >= 1; d >>= 1) s += __shfl_xor(s, d, 64);
    if (lane == 0) sumx[b] = s;
}

// part[seg][b][o] = sum_{k in seg} x_bf[b][k] * qw_bf[o][k]
__global__ __launch_bounds__(WPB * 64)
void qlinear_mfma(const unsigned short* __restrict__ xbf,  // [BATCH][IN_F] bf16
                  const float* __restrict__ qw,            // [OUT_F][IN_F]
                  float* __restrict__ part)                // [KSPLIT][BATCH][OUT_F]
{
    const int lane = threadIdx.x & 63;
    const int wave = threadIdx.x >> 6;
    const int wg   = blockIdx.x * WPB + wave;      // 0 .. KSPLIT*NT-1
    const int seg  = wg / NT;
    const int tile = wg - seg * NT;
    const int n0   = tile * 16;
    const int lm   = lane & 15;          // m (A) / n (B) index within tile
    const int lk   = (lane >> 4) * 8;    // k-base within 32-block

    // A-frag: x_bf[m=lm][kb + lk .. +8]   (8 bf16 = 16 B, L1/L2-hot)
    const unsigned short* xp = xbf + lm * IN_F + seg * SEG + lk;
    // B-frag: qw[n0+lm][kb + lk .. +8]    (8 f32 = 32 B, the HBM stream)
    const float* qp = qw + (size_t)(n0 + lm) * IN_F + seg * SEG + lk;

    f32x4 acc = {0.0f, 0.0f, 0.0f, 0.0f};

#pragma unroll 4
    for (int it = 0; it < ITERS; ++it) {
        const bf16x8 a = *reinterpret_cast<const bf16x8*>(xp + it * 32);
        const float4 q0 = *reinterpret_cast<const float4*>(qp + it * 32);
        const float4 q1 = *reinterpret_cast<const float4*>(qp + it * 32 + 4);
        bf16x8 bq;
        bq[0] = f2bf(q0.x); bq[1] = f2bf(q0.y);
        bq[2] = f2bf(q0.z); bq[3] = f2bf(q0.w);
        bq[4] = f2bf(q1.x); bq[5] = f2bf(q1.y);
        bq[6] = f2bf(q1.z); bq[7] = f2bf(q1.w);
        acc = __builtin_amdgcn_mfma_f32_16x16x32_bf16(a, bq, acc, 0, 0, 0);
    }

    // C/D layout (m89-verified): col = lane&15, row = (lane>>4)*4 + j.
    const int m0 = (lane >> 4) * 4;
    float* pp = part + ((size_t)seg * BATCH + m0) * OUT_F + n0 + lm;
#pragma unroll
    for (int j = 0; j < 4; ++j)
        pp[(size_t)j * OUT_F] = acc[j];
}

// y = scale * (sum_seg part[seg][b][o] - zp * sumx[b]) + bias[o]
__global__ __launch_bounds__(256)
void qlinear_stage2(const float* __restrict__ part,
                    const float* __restrict__ sumx,
                    const float* __restrict__ scale_p,
                    const float* __restrict__ zp_p,
                    const float* __restrict__ bias,
                    float* __restrict__ y)
{
    const int i = (blockIdx.x * 256 + threadIdx.x) * 4;   // over BATCH*OUT_F
    const float s  = scale_p[0];
    const float zc = zp_p[0] * sumx[i >> 13];             // b = i / OUT_F
    float4 sum = {0.0f, 0.0f, 0.0f, 0.0f};
#pragma unroll
    for (int seg = 0; seg < KSPLIT; ++seg) {
        const float4 p = *reinterpret_cast<const float4*>(
            part + (size_t)seg * BATCH * OUT_F + i);
        sum.x += p.x; sum.y += p.y; sum.z += p.z; sum.w += p.w;
    }
    const float4 bv = *reinterpret_cast<const float4*>(bias + (i & (OUT_F - 1)));
    float4 out;
    out.x = s * (sum.x - zc) + bv.x;
    out.y = s * (sum.y - zc) + bv.y;
    out.z = s * (sum.z - zc) + bv.z;
    out.w = s * (sum.w - zc) + bv.w;
    *reinterpret_cast<float4*>(y + i) = out;
}

extern "C" void kernel_launch(void* const* d_in, const int* in_sizes, int n_in,
                              void* d_out, int out_size, void* d_ws, size_t ws_size,
                              hipStream_t stream) {
    const float* x     = (const float*)d_in[0];
    const float* qw    = (const float*)d_in[1];
    const float* scale = (const float*)d_in[2];
    const float* zp    = (const float*)d_in[3];
    const float* bias  = (const float*)d_in[4];
    float* y = (float*)d_out;

    // ws layout: part (4 MB) | xbf (256 KB) | sumx (64 B)
    float* part = (float*)d_ws;
    unsigned short* xbf = (unsigned short*)(part + (size_t)KSPLIT * BATCH * OUT_F);
    float* sumx = (float*)(xbf + (size_t)BATCH * IN_F);

    prep_kernel<<<BATCH, 64, 0, stream>>>(x, xbf, sumx);
    qlinear_mfma<<<KSPLIT * NT / WPB, WPB * 64, 0, stream>>>(xbf, qw, part);
    const int n_elem_blocks = (BATCH * OUT_F / 4) / 256;  // 128
    qlinear_stage2<<<n_elem_blocks, 256, 0, stream>>>(part, sumx, scale, zp, bias, y);
}